// Round 4
// baseline (47.846 us; speedup 1.0000x reference)
//
#include <hip/hip_runtime.h>
#include <math.h>

// Problem constants
#define T_LEN 512
#define B_DIM 16
#define K_DIM 64
#define N_DIM 64
#define M_DIM 128

// ---------------------------------------------------------------------------
// K1: Bp[k][n] = prod_{i != n} 1/(1 - e^{i(ang_i - ang_n)})
//     using 1/(1-e^{i d}) = 0.5 + 0.5*i*cot(d/2)
// grid 64 blocks (k) x 64 threads (n)   (~1 us, proven)
// ---------------------------------------------------------------------------
__global__ void k_bp(const float* __restrict__ theta, float2* __restrict__ bp) {
    int k = blockIdx.x;
    int j = threadIdx.x;
    __shared__ float ang[N_DIM];
    float a = (j < 32) ? theta[k * 32 + j] : -theta[k * 32 + (j - 32)];
    ang[j] = a;
    __syncthreads();
    double pr = 1.0, pi = 0.0;
    for (int i = 0; i < N_DIM; ++i) {
        if (i == j) continue;
        float d = ang[i] - a;
        float s, c;
        sincosf(0.5f * d, &s, &c);
        float ti = 0.5f * (c / s);     // 0.5*cot(d/2)
        double nr = pr * 0.5 - pi * (double)ti;
        double ni = pr * (double)ti + pi * 0.5;
        pr = nr; pi = ni;
    }
    bp[k * N_DIM + j] = make_float2((float)pr, (float)pi);
}

// ---------------------------------------------------------------------------
// K2: sT[k][n][b] = Bp[k][n] * sum_{t=1}^{511} lam^{511-t} xc_t,  xc_t = x[t-1][b][k]
// grid 1024 blocks (b,k) x 256 threads (wave c = time-chunk, lane n)
// - direct thread-parallel gather of the x column into LDS (latency hidden
//   across 256 threads; no transpose kernel, no xt round-trip)
// - xs shifted by 1 (xs[0]=0) so each 128-step chunk is float4-aligned:
//   inner loop = 32 x ds_read_b128 (uniform broadcast) + 4 FMA-steps each
// - 4 chunks combined with lam^{128/256/384} via double squarings
// ---------------------------------------------------------------------------
__global__ __launch_bounds__(256) void k_state(const float* __restrict__ x,
                        const float* __restrict__ theta,
                        const float2* __restrict__ bp, float2* __restrict__ sT) {
    int id = blockIdx.x;
    // XCD chunked swizzle: blocks sharing b land on the same XCD (L2 line reuse)
    int logical = (id & 7) * 128 + (id >> 3);
    int b = logical >> 6;
    int k = logical & 63;
    int tid = threadIdx.x;
    int c = tid >> 6;   // chunk index == wave index
    int n = tid & 63;

    __shared__ float xs[T_LEN];          // xs[i] = xc_i (xs[0] = 0)
    __shared__ float2 part[4][N_DIM];

    // parallel gather: xs[1+u] = x[u][b][k] for u = 0..510
    {
        int bk = logical;                // b*64 + k
        float v0 = x[tid * (B_DIM * K_DIM) + bk];
        xs[1 + tid] = v0;
        if (tid < 255) {
            float v1 = x[(tid + 256) * (B_DIM * K_DIM) + bk];
            xs[257 + tid] = v1;
        }
        if (tid == 255) xs[0] = 0.f;
    }

    float a = (n < 32) ? theta[k * 32 + n] : -theta[k * 32 + (n - 32)];
    float li, lr;
    sincosf(a, &li, &lr);   // lam = (lr, li)
    __syncthreads();

    float sr = 0.f, si = 0.f;
    const float4* xq = ((const float4*)xs) + 32 * c;
    #pragma unroll 4
    for (int q = 0; q < 32; ++q) {
        float4 xv = xq[q];
        float t0, u0;
        t0 = fmaf(-li, si, xv.x); u0 = li * sr;
        sr = fmaf(lr, sr, t0);    si = fmaf(lr, si, u0);
        t0 = fmaf(-li, si, xv.y); u0 = li * sr;
        sr = fmaf(lr, sr, t0);    si = fmaf(lr, si, u0);
        t0 = fmaf(-li, si, xv.z); u0 = li * sr;
        sr = fmaf(lr, sr, t0);    si = fmaf(lr, si, u0);
        t0 = fmaf(-li, si, xv.w); u0 = li * sr;
        sr = fmaf(lr, sr, t0);    si = fmaf(lr, si, u0);
    }
    part[c][n] = make_float2(sr, si);
    __syncthreads();

    if (tid < 64) {
        // lam^128 by 7 squarings in double, then ^256, ^384
        double ar = (double)lr, ai = (double)li;
        #pragma unroll
        for (int q = 0; q < 7; ++q) {
            double t1 = ar * ar - ai * ai;
            double t2 = 2.0 * ar * ai;
            ar = t1; ai = t2;
        }
        double b2r = ar * ar - ai * ai, b2i = 2.0 * ar * ai;          // ^256
        double b3r = b2r * ar - b2i * ai, b3i = b2r * ai + b2i * ar;  // ^384
        float2 s0 = part[0][n], s1 = part[1][n], s2 = part[2][n], s3 = part[3][n];
        double gr = b3r * s0.x - b3i * s0.y + b2r * s1.x - b2i * s1.y
                  + ar  * s2.x - ai  * s2.y + (double)s3.x;
        double gi = b3r * s0.y + b3i * s0.x + b2r * s1.y + b2i * s1.x
                  + ar  * s2.y + ai  * s2.x + (double)s3.y;
        float2 bv = bp[k * N_DIM + n];
        float rr = (float)(gr * bv.x - gi * bv.y);
        float ri = (float)(gr * bv.y + gi * bv.x);
        sT[(k * N_DIM + n) * B_DIM + b] = make_float2(rr, ri);
    }
}

// ---------------------------------------------------------------------------
// K3: out[b][m] = (1/K) * ( sum_{k,n} sT[k][n][b] * exp(lnC[k][m][n])
//                           + sum_k x[510][b][k] * D[k][m] ) + Do[m]
// grid 128 blocks (m) x 256 threads; sT read as float4 (2 complex / load)
// ---------------------------------------------------------------------------
__global__ void k_out(const float* __restrict__ lnCr, const float* __restrict__ lnCi,
                      const float* __restrict__ D, const float* __restrict__ Do_,
                      const float* __restrict__ x, const float2* __restrict__ sT,
                      float* __restrict__ out, int cplx) {
    int m = blockIdx.x;
    int tid = threadIdx.x;
    float accr[B_DIM], acci[B_DIM];
    #pragma unroll
    for (int b = 0; b < B_DIM; ++b) { accr[b] = 0.f; acci[b] = 0.f; }

    for (int it = 0; it < 16; ++it) {
        int p = it * 256 + tid;        // (k,n) pair index
        int k = p >> 6;
        int n = p & 63;
        int ci = k * (M_DIM * N_DIM) + m * N_DIM + n;
        float er = expf(lnCr[ci]);
        float sn, cs;
        sincosf(lnCi[ci], &sn, &cs);
        float cr = er * cs, cim = er * sn;
        const float4* sp = (const float4*)(sT + p * B_DIM);
        #pragma unroll
        for (int h = 0; h < 8; ++h) {
            float4 v = sp[h];          // two complex: (v.x,v.y), (v.z,v.w)
            int b0 = 2 * h;
            accr[b0]     = fmaf(v.x, cr, fmaf(-v.y, cim, accr[b0]));
            acci[b0]     = fmaf(v.x, cim, fmaf(v.y, cr, acci[b0]));
            accr[b0 + 1] = fmaf(v.z, cr, fmaf(-v.w, cim, accr[b0 + 1]));
            acci[b0 + 1] = fmaf(v.z, cim, fmaf(v.w, cr, acci[b0 + 1]));
        }
    }

    __shared__ float2 red[B_DIM][256];
    #pragma unroll
    for (int b = 0; b < B_DIM; ++b) red[b][tid] = make_float2(accr[b], acci[b]);
    __syncthreads();
    // stage 1: 256 threads -> 16 partials per b
    {
        int b = tid >> 4, seg = tid & 15;
        float2 sum = make_float2(0.f, 0.f);
        #pragma unroll
        for (int q = 0; q < 16; ++q) {
            float2 v = red[b][seg * 16 + q];
            sum.x += v.x; sum.y += v.y;
        }
        __syncthreads();               // all reads done before overwrite
        red[b][seg] = sum;
    }
    __syncthreads();
    if (tid < B_DIM) {
        int b = tid;
        float sumr = 0.f, sumi = 0.f;
        #pragma unroll
        for (int q = 0; q < 16; ++q) {
            float2 v = red[b][q];
            sumr += v.x; sumi += v.y;
        }
        // Dx term: x[T-2][b][k] * D[k][m]
        float dx = 0.f;
        const float* xl = x + 510 * (B_DIM * K_DIM) + b * K_DIM;
        #pragma unroll 8
        for (int kk = 0; kk < K_DIM; ++kk)
            dx = fmaf(xl[kk], D[kk * M_DIM + m], dx);
        float outr = (sumr + dx) * (1.0f / 64.0f) + Do_[m];
        float outi = sumi * (1.0f / 64.0f);
        if (cplx) {
            ((float2*)out)[b * M_DIM + m] = make_float2(outr, outi);
        } else {
            out[b * M_DIM + m] = outr;
        }
    }
}

// ---------------------------------------------------------------------------
extern "C" void kernel_launch(void* const* d_in, const int* in_sizes, int n_in,
                              void* d_out, int out_size, void* d_ws, size_t ws_size,
                              hipStream_t stream) {
    const float* x     = (const float*)d_in[0];
    const float* theta = (const float*)d_in[1];
    const float* lnCr  = (const float*)d_in[2];
    const float* lnCi  = (const float*)d_in[3];
    const float* D     = (const float*)d_in[4];
    const float* Do_   = (const float*)d_in[5];

    float2* bp = (float2*)d_ws;                    // 64*64 float2    =  32 KB
    float2* sT = bp + K_DIM * N_DIM;               // 4096*16 float2  = 512 KB

    // out_size == B*M (2048): real-part-only float32 output
    // out_size == 2*B*M (4096): interleaved complex64 viewed as float32
    int cplx = (out_size >= 2 * B_DIM * M_DIM) ? 1 : 0;

    k_bp   <<<K_DIM, N_DIM, 0, stream>>>(theta, bp);
    k_state<<<B_DIM * K_DIM, 256, 0, stream>>>(x, theta, bp, sT);
    k_out  <<<M_DIM, 256, 0, stream>>>(lnCr, lnCi, D, Do_, x, sT, (float*)d_out, cplx);
}

// Round 5
// 47.131 us; speedup vs baseline: 1.0152x; 1.0152x over previous
//
#include <hip/hip_runtime.h>
#include <math.h>

// Problem constants
#define T_LEN 512
#define B_DIM 16
#define K_DIM 64
#define N_DIM 64
#define M_DIM 128

// ---------------------------------------------------------------------------
// K_state (fused Bp + recurrence):
//   sT[k][n][b] = Bp[k][n] * sum_{t=1}^{511} lam^{511-t} xc_t, xc_t = x[t-1][b][k]
//   Bp[k][n] = prod_{i != n} 1/(1 - e^{i(ang_i - ang_n)}) via 0.5 + 0.5*i*cot(d/2)
// grid 1024 blocks (b,k) x 256 threads (wave c = time-chunk, lane n)
// - thread-parallel gather of the x column into LDS (latency hidden)
// - xs shifted by 1 (xs[0]=0) so each 128-step chunk is float4-aligned:
//   inner loop = 32 x ds_read_b128 (uniform broadcast) + 4 FMA-steps each
// - 4 chunks combined with lam^{128/256/384} via double squarings
// - wave 0 computes the 63-term Bp product in the tail (redundant per-b, ~1us)
// ---------------------------------------------------------------------------
__global__ __launch_bounds__(256) void k_state(const float* __restrict__ x,
                        const float* __restrict__ theta,
                        float2* __restrict__ sT) {
    int id = blockIdx.x;
    // XCD chunked swizzle: blocks sharing b land on the same XCD (L2 line reuse)
    int logical = (id & 7) * 128 + (id >> 3);
    int b = logical >> 6;
    int k = logical & 63;
    int tid = threadIdx.x;
    int c = tid >> 6;   // chunk index == wave index
    int n = tid & 63;

    __shared__ float xs[T_LEN];          // xs[i] = xc_i (xs[0] = 0)
    __shared__ float ang[N_DIM];
    __shared__ float2 part[4][N_DIM];

    // parallel gather: xs[1+u] = x[u][b][k] for u = 0..510
    {
        int bk = logical;                // b*64 + k
        float v0 = x[tid * (B_DIM * K_DIM) + bk];
        xs[1 + tid] = v0;
        if (tid < 255) {
            float v1 = x[(tid + 256) * (B_DIM * K_DIM) + bk];
            xs[257 + tid] = v1;
        }
        if (tid == 255) xs[0] = 0.f;
    }

    float a = (n < 32) ? theta[k * 32 + n] : -theta[k * 32 + (n - 32)];
    if (tid < 64) ang[tid] = a;
    float li, lr;
    sincosf(a, &li, &lr);   // lam = (lr, li)
    __syncthreads();

    float sr = 0.f, si = 0.f;
    const float4* xq = ((const float4*)xs) + 32 * c;
    #pragma unroll 4
    for (int q = 0; q < 32; ++q) {
        float4 xv = xq[q];
        float t0, u0;
        t0 = fmaf(-li, si, xv.x); u0 = li * sr;
        sr = fmaf(lr, sr, t0);    si = fmaf(lr, si, u0);
        t0 = fmaf(-li, si, xv.y); u0 = li * sr;
        sr = fmaf(lr, sr, t0);    si = fmaf(lr, si, u0);
        t0 = fmaf(-li, si, xv.z); u0 = li * sr;
        sr = fmaf(lr, sr, t0);    si = fmaf(lr, si, u0);
        t0 = fmaf(-li, si, xv.w); u0 = li * sr;
        sr = fmaf(lr, sr, t0);    si = fmaf(lr, si, u0);
    }
    part[c][n] = make_float2(sr, si);
    __syncthreads();

    if (tid < 64) {
        // Bp product: prod_{i != n} (0.5 + 0.5*i*cot((ang_i - ang_n)/2))
        double pr = 1.0, pi = 0.0;
        for (int i = 0; i < N_DIM; ++i) {
            if (i == tid) continue;
            float d = ang[i] - a;
            float s, cc;
            sincosf(0.5f * d, &s, &cc);
            float ti = 0.5f * (cc / s);     // 0.5*cot(d/2)
            double nr = pr * 0.5 - pi * (double)ti;
            double ni = pr * (double)ti + pi * 0.5;
            pr = nr; pi = ni;
        }
        // lam^128 by 7 squarings in double, then ^256, ^384
        double ar = (double)lr, ai = (double)li;
        #pragma unroll
        for (int q = 0; q < 7; ++q) {
            double t1 = ar * ar - ai * ai;
            double t2 = 2.0 * ar * ai;
            ar = t1; ai = t2;
        }
        double b2r = ar * ar - ai * ai, b2i = 2.0 * ar * ai;          // ^256
        double b3r = b2r * ar - b2i * ai, b3i = b2r * ai + b2i * ar;  // ^384
        float2 s0 = part[0][n], s1 = part[1][n], s2 = part[2][n], s3 = part[3][n];
        double gr = b3r * s0.x - b3i * s0.y + b2r * s1.x - b2i * s1.y
                  + ar  * s2.x - ai  * s2.y + (double)s3.x;
        double gi = b3r * s0.y + b3i * s0.x + b2r * s1.y + b2i * s1.x
                  + ar  * s2.y + ai  * s2.x + (double)s3.y;
        float rr = (float)(gr * pr - gi * pi);
        float ri = (float)(gr * pi + gi * pr);
        sT[(k * N_DIM + n) * B_DIM + b] = make_float2(rr, ri);
    }
}

// ---------------------------------------------------------------------------
// K3: out[b][m] = (1/K) * ( sum_{k,n} sT[k][n][b] * exp(lnC[k][m][n])
//                           + sum_k x[510][b][k] * D[k][m] ) + Do[m]
// grid 128 blocks (m) x 256 threads; sT read as float4 (2 complex / load)
// ---------------------------------------------------------------------------
__global__ void k_out(const float* __restrict__ lnCr, const float* __restrict__ lnCi,
                      const float* __restrict__ D, const float* __restrict__ Do_,
                      const float* __restrict__ x, const float2* __restrict__ sT,
                      float* __restrict__ out, int cplx) {
    int m = blockIdx.x;
    int tid = threadIdx.x;
    float accr[B_DIM], acci[B_DIM];
    #pragma unroll
    for (int b = 0; b < B_DIM; ++b) { accr[b] = 0.f; acci[b] = 0.f; }

    for (int it = 0; it < 16; ++it) {
        int p = it * 256 + tid;        // (k,n) pair index
        int k = p >> 6;
        int n = p & 63;
        int ci = k * (M_DIM * N_DIM) + m * N_DIM + n;
        float er = expf(lnCr[ci]);
        float sn, cs;
        sincosf(lnCi[ci], &sn, &cs);
        float cr = er * cs, cim = er * sn;
        const float4* sp = (const float4*)(sT + p * B_DIM);
        #pragma unroll
        for (int h = 0; h < 8; ++h) {
            float4 v = sp[h];          // two complex: (v.x,v.y), (v.z,v.w)
            int b0 = 2 * h;
            accr[b0]     = fmaf(v.x, cr, fmaf(-v.y, cim, accr[b0]));
            acci[b0]     = fmaf(v.x, cim, fmaf(v.y, cr, acci[b0]));
            accr[b0 + 1] = fmaf(v.z, cr, fmaf(-v.w, cim, accr[b0 + 1]));
            acci[b0 + 1] = fmaf(v.z, cim, fmaf(v.w, cr, acci[b0 + 1]));
        }
    }

    __shared__ float2 red[B_DIM][256];
    #pragma unroll
    for (int b = 0; b < B_DIM; ++b) red[b][tid] = make_float2(accr[b], acci[b]);
    __syncthreads();
    // stage 1: 256 threads -> 16 partials per b
    {
        int b = tid >> 4, seg = tid & 15;
        float2 sum = make_float2(0.f, 0.f);
        #pragma unroll
        for (int q = 0; q < 16; ++q) {
            float2 v = red[b][seg * 16 + q];
            sum.x += v.x; sum.y += v.y;
        }
        __syncthreads();               // all reads done before overwrite
        red[b][seg] = sum;
    }
    __syncthreads();
    if (tid < B_DIM) {
        int b = tid;
        float sumr = 0.f, sumi = 0.f;
        #pragma unroll
        for (int q = 0; q < 16; ++q) {
            float2 v = red[b][q];
            sumr += v.x; sumi += v.y;
        }
        // Dx term: x[T-2][b][k] * D[k][m]
        float dx = 0.f;
        const float* xl = x + 510 * (B_DIM * K_DIM) + b * K_DIM;
        #pragma unroll 8
        for (int kk = 0; kk < K_DIM; ++kk)
            dx = fmaf(xl[kk], D[kk * M_DIM + m], dx);
        float outr = (sumr + dx) * (1.0f / 64.0f) + Do_[m];
        float outi = sumi * (1.0f / 64.0f);
        if (cplx) {
            ((float2*)out)[b * M_DIM + m] = make_float2(outr, outi);
        } else {
            out[b * M_DIM + m] = outr;
        }
    }
}

// ---------------------------------------------------------------------------
extern "C" void kernel_launch(void* const* d_in, const int* in_sizes, int n_in,
                              void* d_out, int out_size, void* d_ws, size_t ws_size,
                              hipStream_t stream) {
    const float* x     = (const float*)d_in[0];
    const float* theta = (const float*)d_in[1];
    const float* lnCr  = (const float*)d_in[2];
    const float* lnCi  = (const float*)d_in[3];
    const float* D     = (const float*)d_in[4];
    const float* Do_   = (const float*)d_in[5];

    float2* sT = (float2*)d_ws;                    // 4096*16 float2 = 512 KB

    // out_size == B*M (2048): real-part-only float32 output
    // out_size == 2*B*M (4096): interleaved complex64 viewed as float32
    int cplx = (out_size >= 2 * B_DIM * M_DIM) ? 1 : 0;

    k_state<<<B_DIM * K_DIM, 256, 0, stream>>>(x, theta, sT);
    k_out  <<<M_DIM, 256, 0, stream>>>(lnCr, lnCi, D, Do_, x, sT, (float*)d_out, cplx);
}